// Round 1
// baseline (2021.208 us; speedup 1.0000x reference)
//
#include <hip/hip_runtime.h>
#include <math.h>

// Problem constants
#define BB 64
#define NN 100
#define HH 128
#define T3 384

// Output layout (floats, concatenated in return order)
#define O0 0            // sample_logprob [64,99]
#define O1 6336         // sample_distance [64,1]
#define O2 6400         // greedy_distance [64,1]
#define O3 6464         // predict_matrix [64,100,100,2]
#define O4 1286464      // greedy_solution_matrix [64,100,100]

#define TINYF 1.17549435e-38f

// ---------------- threefry2x32 (exact JAX implementation) ----------------
__device__ __forceinline__ unsigned rotl32(unsigned x, int d) {
    return (x << d) | (x >> (32 - d));
}

__device__ __forceinline__ void tf2x32(unsigned ks0, unsigned ks1,
                                       unsigned x0, unsigned x1,
                                       unsigned& o0, unsigned& o1) {
    unsigned ks2 = ks0 ^ ks1 ^ 0x1BD11BDAu;
    x0 += ks0; x1 += ks1;
    // group 1 (rot 13,15,26,6)
    x0 += x1; x1 = rotl32(x1, 13); x1 ^= x0;
    x0 += x1; x1 = rotl32(x1, 15); x1 ^= x0;
    x0 += x1; x1 = rotl32(x1, 26); x1 ^= x0;
    x0 += x1; x1 = rotl32(x1, 6);  x1 ^= x0;
    x0 += ks1; x1 += ks2 + 1u;
    // group 2 (rot 17,29,16,24)
    x0 += x1; x1 = rotl32(x1, 17); x1 ^= x0;
    x0 += x1; x1 = rotl32(x1, 29); x1 ^= x0;
    x0 += x1; x1 = rotl32(x1, 16); x1 ^= x0;
    x0 += x1; x1 = rotl32(x1, 24); x1 ^= x0;
    x0 += ks2; x1 += ks0 + 2u;
    // group 3
    x0 += x1; x1 = rotl32(x1, 13); x1 ^= x0;
    x0 += x1; x1 = rotl32(x1, 15); x1 ^= x0;
    x0 += x1; x1 = rotl32(x1, 26); x1 ^= x0;
    x0 += x1; x1 = rotl32(x1, 6);  x1 ^= x0;
    x0 += ks0; x1 += ks1 + 3u;
    // group 4
    x0 += x1; x1 = rotl32(x1, 17); x1 ^= x0;
    x0 += x1; x1 = rotl32(x1, 29); x1 ^= x0;
    x0 += x1; x1 = rotl32(x1, 16); x1 ^= x0;
    x0 += x1; x1 = rotl32(x1, 24); x1 ^= x0;
    x0 += ks1; x1 += ks2 + 4u;
    // group 5
    x0 += x1; x1 = rotl32(x1, 13); x1 ^= x0;
    x0 += x1; x1 = rotl32(x1, 15); x1 ^= x0;
    x0 += x1; x1 = rotl32(x1, 26); x1 ^= x0;
    x0 += x1; x1 = rotl32(x1, 6);  x1 ^= x0;
    x0 += ks2; x1 += ks0 + 5u;
    o0 = x0; o1 = x1;
}

// gumbel noise for flat index f under key (k0,k1), partitionable semantics:
// bits = o0 ^ o1 of TF(key, (hi=0, lo=f)); uniform in [tiny, 1); -log(-log(u))
__device__ __forceinline__ float gumbel_f(unsigned k0, unsigned k1, unsigned f) {
    unsigned o0, o1;
    tf2x32(k0, k1, 0u, f, o0, o1);
    unsigned bits = o0 ^ o1;
    float u01 = __uint_as_float((bits >> 9) | 0x3F800000u) - 1.0f;
    float u = fmaxf(TINYF, u01 * (1.0f - TINYF) + TINYF);
    return -logf(-logf(u));
}

// ---------------- encoder kernels ----------------

// h0 = relu([node|demand] @ Wn0 + bn0) : [6400,128]
__global__ void k_embed(const float* __restrict__ node, const float* __restrict__ demand,
                        const float* __restrict__ Wn0, const float* __restrict__ bn0,
                        float* __restrict__ h) {
    int idx = blockIdx.x * 256 + threadIdx.x;
    if (idx >= BB * NN * HH) return;
    int r = idx >> 7, c = idx & 127;
    float v = node[r * 2] * Wn0[c] + node[r * 2 + 1] * Wn0[128 + c]
            + demand[r] * Wn0[256 + c] + bn0[c];
    h[idx] = fmaxf(v, 0.0f);
}

// A = softmax(-dis, -1) row-wise; one wave per row
__global__ void k_adj(const float* __restrict__ dis, float* __restrict__ A) {
    int row = blockIdx.x;                 // b*100 + i
    const float* d = dis + row * NN;
    int l = threadIdx.x;                  // 0..63
    float v0 = (l < NN) ? -d[l] : -__builtin_inff();
    float v1 = (l + 64 < NN) ? -d[l + 64] : -__builtin_inff();
    float m = fmaxf(v0, v1);
    for (int off = 32; off > 0; off >>= 1) m = fmaxf(m, __shfl_xor(m, off));
    float e0 = (l < NN) ? expf(v0 - m) : 0.0f;
    float e1 = (l + 64 < NN) ? expf(v1 - m) : 0.0f;
    float s = e0 + e1;
    for (int off = 32; off > 0; off >>= 1) s += __shfl_xor(s, off);
    float inv = 1.0f / s;
    if (l < NN) A[row * NN + l] = e0 * inv;
    if (l + 64 < NN) A[row * NN + l + 64] = e1 * inv;
}

// hw = h @ W  (6400x128 @ 128x128); 8 rows per block, 2 row-groups x 128 cols
__global__ void k_hw(const float* __restrict__ h, const float* __restrict__ W,
                     float* __restrict__ out) {
    __shared__ float hs[8 * 128];
    int block_row = blockIdx.x * 8;
    int tid = threadIdx.x;
    int col = tid & 127;
    int rg = tid >> 7;
    for (int i = tid; i < 8 * 128; i += 256) hs[i] = h[block_row * 128 + i];
    __syncthreads();
    float acc[4] = {0.f, 0.f, 0.f, 0.f};
    for (int k = 0; k < 128; k++) {
        float w = W[k * 128 + col];
#pragma unroll
        for (int r = 0; r < 4; r++) acc[r] += hs[(rg + 2 * r) * 128 + k] * w;
    }
#pragma unroll
    for (int r = 0; r < 4; r++)
        out[(block_row + rg + 2 * r) * 128 + col] = acc[r];
}

// h' = relu(h @ Ws + A_batched @ hw); 4 rows (same batch) per block
__global__ void k_agg(const float* __restrict__ h, const float* __restrict__ Ws,
                      const float* __restrict__ A, const float* __restrict__ hw,
                      float* __restrict__ out) {
    __shared__ float hs[4 * 128];
    __shared__ float As[4 * 100];
    int b = blockIdx.x / 25;
    int i0 = (blockIdx.x % 25) * 4;
    int tid = threadIdx.x;
    int col = tid & 127;
    int rg = tid >> 7;
    int rowbase = b * NN + i0;
    for (int idx = tid; idx < 4 * 128; idx += 256) hs[idx] = h[rowbase * 128 + idx];
    for (int idx = tid; idx < 4 * 100; idx += 256) As[idx] = A[rowbase * 100 + idx];
    __syncthreads();
    float acc0 = 0.f, acc1 = 0.f;
    for (int k = 0; k < 128; k++) {
        float w = Ws[k * 128 + col];
        acc0 += hs[rg * 128 + k] * w;
        acc1 += hs[(rg + 2) * 128 + k] * w;
    }
    const float* hwb = hw + b * NN * 128;
    for (int j = 0; j < NN; j++) {
        float v = hwb[j * 128 + col];
        acc0 += As[rg * 100 + j] * v;
        acc1 += As[(rg + 2) * 100 + j] * v;
    }
    out[(rowbase + rg) * 128 + col]     = fmaxf(acc0, 0.0f);
    out[(rowbase + rg + 2) * 128 + col] = fmaxf(acc1, 0.0f);
}

// predict_matrix: fused relu(d*We+be) @ Wc + bc -> softmax2. Never materializes e.
__global__ void k_predict(const float* __restrict__ dis, const float* __restrict__ We,
                          const float* __restrict__ be, const float* __restrict__ Wc,
                          const float* __restrict__ bc, float* __restrict__ out3) {
    __shared__ float sWe[128], sbe[128], sc0[128], sc1[128];
    int tid = threadIdx.x;
    if (tid < 128) {
        sWe[tid] = We[tid];
        sbe[tid] = be[tid];
        sc0[tid] = Wc[tid * 2];
        sc1[tid] = Wc[tid * 2 + 1];
    }
    __syncthreads();
    float b0 = bc[0], b1 = bc[1];
    for (int pos = blockIdx.x * 256 + tid; pos < BB * NN * NN; pos += gridDim.x * 256) {
        float d = dis[pos];
        float a0 = b0, a1 = b1;
        for (int k = 0; k < 128; k++) {
            float e = fmaxf(d * sWe[k] + sbe[k], 0.0f);
            a0 += e * sc0[k];
            a1 += e * sc1[k];
        }
        float m = fmaxf(a0, a1);
        float p0 = expf(a0 - m), p1 = expf(a1 - m);
        float inv = 1.0f / (p0 + p1);
        out3[pos * 2]     = p0 * inv;
        out3[pos * 2 + 1] = p1 * inv;
    }
}

__global__ void k_zero(float* __restrict__ p, int n) {
    int i = blockIdx.x * 256 + threadIdx.x;
    if (i < n) p[i] = 0.0f;
}

// ---------------- decoder ----------------

__device__ __forceinline__ void gru_layer(const float* __restrict__ xin,
                                          float* __restrict__ hstate,
                                          const float* __restrict__ Wih,
                                          const float* __restrict__ Whh,
                                          const float* __restrict__ bih,
                                          const float* __restrict__ bhh,
                                          float* gi, float* gh, int tid) {
    for (int j = tid; j < T3; j += 256) {
        float ai = bih[j], ah = bhh[j];
        const float* wi = Wih + j;
        const float* wh = Whh + j;
        for (int k = 0; k < 128; k++) {
            ai += xin[k] * wi[k * T3];
            ah += hstate[k] * wh[k * T3];
        }
        gi[j] = ai; gh[j] = ah;
    }
    __syncthreads();
    if (tid < 128) {
        float r = 1.0f / (1.0f + expf(-(gi[tid] + gh[tid])));
        float z = 1.0f / (1.0f + expf(-(gi[128 + tid] + gh[128 + tid])));
        float n = tanhf(gi[256 + tid] + r * gh[256 + tid]);
        hstate[tid] = (1.0f - z) * n + z * hstate[tid];
    }
    __syncthreads();
}

// grid = 128 blocks: blockIdx/2 = batch, blockIdx&1 = greedy flag
__global__ __launch_bounds__(256) void k_decode(
    const float* __restrict__ x,        // final encoder h [64,100,128]
    const float* __restrict__ dis,      // [64,100,100]
    const float* __restrict__ Wih,      // [2,128,384]
    const float* __restrict__ Whh,      // [2,128,384]
    const float* __restrict__ bih,      // [2,384]
    const float* __restrict__ bhh,      // [2,384]
    const float* __restrict__ Wq,       // [128,128]
    float* __restrict__ out) {
    __shared__ float xs[NN * 129];      // padded stride 129 to kill bank conflicts
    __shared__ float h0[128], h1[128];
    __shared__ float gi[T3], gh[T3];
    __shared__ float q[128];
    __shared__ float logits[NN];
    __shared__ float s_m, s_s;
    __shared__ int s_ind;

    const int tid = threadIdx.x;
    const int b = blockIdx.x >> 1;
    const int greedy = blockIdx.x & 1;
    const float SCALE = (float)(1.0 / (double)sqrtf(128.0f));  // matches 1.0/np.sqrt(128).astype(f32)

    for (int idx = tid; idx < NN * 128; idx += 256) {
        int r = idx >> 7, c = idx & 127;
        xs[r * 129 + c] = x[(b * NN + r) * 128 + c];
    }
    if (tid < 128) { h0[tid] = 0.0f; h1[tid] = 0.0f; }

    // k1 = first key of split(key(42)) under partitionable foldlike split
    unsigned kk0, kk1;
    tf2x32(0u, 42u, 0u, 0u, kk0, kk1);

    int last = 0;
    float dist = 0.0f;
    __syncthreads();

    for (int t = 0; t < NN - 1; t++) {
        // k, sk = split(k):  k' = TF(k,(0,0)), sk = TF(k,(0,1))
        unsigned sk0, sk1, nk0, nk1;
        tf2x32(kk0, kk1, 0u, 1u, sk0, sk1);
        tf2x32(kk0, kk1, 0u, 0u, nk0, nk1);
        kk0 = nk0; kk1 = nk1;

        gru_layer(&xs[last * 129], h0, Wih, Whh, bih, bhh, gi, gh, tid);
        gru_layer(h0, h1, Wih + 128 * T3, Whh + 128 * T3, bih + T3, bhh + T3, gi, gh, tid);

        // q = h1 @ Wq
        if (tid < 128) {
            float acc = 0.0f;
            for (int k = 0; k < 128; k++) acc += h1[k] * Wq[k * 128 + tid];
            q[tid] = acc;
        }
        __syncthreads();

        // logits[n] = scale * <q, x_n>
        if (tid < NN) {
            float acc = 0.0f;
            for (int k = 0; k < 128; k++) acc += q[k] * xs[tid * 129 + k];
            logits[tid] = acc * SCALE;
        }
        __syncthreads();

        // wave-0 reduction: max, sum(exp), argmax(selection value)
        if (tid < 64) {
            float v0 = (tid < NN) ? logits[tid] : -__builtin_inff();
            float v1 = (tid + 64 < NN) ? logits[tid + 64] : -__builtin_inff();
            float m = fmaxf(v0, v1);
            for (int off = 32; off > 0; off >>= 1) m = fmaxf(m, __shfl_xor(m, off));
            float e = ((tid < NN) ? expf(v0 - m) : 0.0f)
                    + ((tid + 64 < NN) ? expf(v1 - m) : 0.0f);
            for (int off = 32; off > 0; off >>= 1) e += __shfl_xor(e, off);
            float a0 = v0, a1 = v1;
            if (!greedy) {
                if (tid < NN)      a0 = v0 + gumbel_f(sk0, sk1, (unsigned)(b * NN + tid));
                if (tid + 64 < NN) a1 = v1 + gumbel_f(sk0, sk1, (unsigned)(b * NN + tid + 64));
            }
            float bv; int bi;
            if (a1 > a0) { bv = a1; bi = tid + 64; } else { bv = a0; bi = tid; }
            for (int off = 32; off > 0; off >>= 1) {
                float ov = __shfl_xor(bv, off);
                int   oi = __shfl_xor(bi, off);
                if (ov > bv || (ov == bv && oi < bi)) { bv = ov; bi = oi; }
            }
            if (tid == 0) { s_m = m; s_s = e; s_ind = bi; }
        }
        __syncthreads();
        int ind = s_ind;
        if (tid == 0) {
            if (!greedy) out[O0 + b * (NN - 1) + t] = logits[ind] - s_m - logf(s_s);
            dist += dis[b * NN * NN + last * NN + ind];
            if (greedy) out[O4 + b * NN * NN + last * NN + ind] = 1.0f;
        }
        last = ind;
        __syncthreads();
    }
    if (tid == 0) {
        if (!greedy) out[O1 + b] = dist;
        else         out[O2 + b] = dist;
    }
}

// ---------------- host launcher ----------------
extern "C" void kernel_launch(void* const* d_in, const int* in_sizes, int n_in,
                              void* d_out, int out_size, void* d_ws, size_t ws_size,
                              hipStream_t stream) {
    (void)in_sizes; (void)n_in; (void)out_size; (void)ws_size;
    const float* node   = (const float*)d_in[0];
    const float* demand = (const float*)d_in[1];
    const float* dis    = (const float*)d_in[2];
    const float* Wn0    = (const float*)d_in[3];
    const float* bn0    = (const float*)d_in[4];
    const float* Ws     = (const float*)d_in[5];
    const float* Wngh   = (const float*)d_in[6];
    const float* We     = (const float*)d_in[7];
    const float* be     = (const float*)d_in[8];
    const float* Wih    = (const float*)d_in[9];
    const float* Whh    = (const float*)d_in[10];
    const float* bih    = (const float*)d_in[11];
    const float* bhh    = (const float*)d_in[12];
    const float* Wq     = (const float*)d_in[13];
    const float* Wc     = (const float*)d_in[14];
    const float* bc     = (const float*)d_in[15];
    float* out = (float*)d_out;
    float* ws  = (float*)d_ws;

    float* hA  = ws;                 // 819200
    float* hB  = ws + 819200;        // 819200
    float* hw  = ws + 1638400;       // 819200
    float* A   = ws + 2457600;       // 640000   (total ~12.4 MB)

    hipLaunchKernelGGL(k_embed, dim3(3200), dim3(256), 0, stream, node, demand, Wn0, bn0, hA);
    hipLaunchKernelGGL(k_adj, dim3(6400), dim3(64), 0, stream, dis, A);

    float* cur = hA;
    float* nxt = hB;
    for (int l = 0; l < 3; l++) {
        hipLaunchKernelGGL(k_hw, dim3(800), dim3(256), 0, stream, cur, Wngh + l * 16384, hw);
        hipLaunchKernelGGL(k_agg, dim3(1600), dim3(256), 0, stream, cur, Ws + l * 16384, A, hw, nxt);
        float* tswap = cur; cur = nxt; nxt = tswap;
    }
    // cur now holds the final encoder output

    hipLaunchKernelGGL(k_predict, dim3(2500), dim3(256), 0, stream, dis, We, be, Wc, bc, out + O3);
    hipLaunchKernelGGL(k_zero, dim3(2500), dim3(256), 0, stream, out + O4, BB * NN * NN);
    hipLaunchKernelGGL(k_decode, dim3(128), dim3(256), 0, stream,
                       cur, dis, Wih, Whh, bih, bhh, Wq, out);
}

// Round 2
// 1054.379 us; speedup vs baseline: 1.9170x; 1.9170x over previous
//
#include <hip/hip_runtime.h>
#include <math.h>

// Problem constants
#define BB 64
#define NN 100
#define HH 128
#define T3 384

// Output layout (floats, concatenated in return order)
#define O0 0            // sample_logprob [64,99]
#define O1 6336         // sample_distance [64,1]
#define O2 6400         // greedy_distance [64,1]
#define O3 6464         // predict_matrix [64,100,100,2]
#define O4 1286464      // greedy_solution_matrix [64,100,100]

#define TINYF 1.17549435e-38f

// ---------------- threefry2x32 (exact JAX implementation) ----------------
__device__ __forceinline__ unsigned rotl32(unsigned x, int d) {
    return (x << d) | (x >> (32 - d));
}

__device__ __forceinline__ void tf2x32(unsigned ks0, unsigned ks1,
                                       unsigned x0, unsigned x1,
                                       unsigned& o0, unsigned& o1) {
    unsigned ks2 = ks0 ^ ks1 ^ 0x1BD11BDAu;
    x0 += ks0; x1 += ks1;
    x0 += x1; x1 = rotl32(x1, 13); x1 ^= x0;
    x0 += x1; x1 = rotl32(x1, 15); x1 ^= x0;
    x0 += x1; x1 = rotl32(x1, 26); x1 ^= x0;
    x0 += x1; x1 = rotl32(x1, 6);  x1 ^= x0;
    x0 += ks1; x1 += ks2 + 1u;
    x0 += x1; x1 = rotl32(x1, 17); x1 ^= x0;
    x0 += x1; x1 = rotl32(x1, 29); x1 ^= x0;
    x0 += x1; x1 = rotl32(x1, 16); x1 ^= x0;
    x0 += x1; x1 = rotl32(x1, 24); x1 ^= x0;
    x0 += ks2; x1 += ks0 + 2u;
    x0 += x1; x1 = rotl32(x1, 13); x1 ^= x0;
    x0 += x1; x1 = rotl32(x1, 15); x1 ^= x0;
    x0 += x1; x1 = rotl32(x1, 26); x1 ^= x0;
    x0 += x1; x1 = rotl32(x1, 6);  x1 ^= x0;
    x0 += ks0; x1 += ks1 + 3u;
    x0 += x1; x1 = rotl32(x1, 17); x1 ^= x0;
    x0 += x1; x1 = rotl32(x1, 29); x1 ^= x0;
    x0 += x1; x1 = rotl32(x1, 16); x1 ^= x0;
    x0 += x1; x1 = rotl32(x1, 24); x1 ^= x0;
    x0 += ks1; x1 += ks2 + 4u;
    x0 += x1; x1 = rotl32(x1, 13); x1 ^= x0;
    x0 += x1; x1 = rotl32(x1, 15); x1 ^= x0;
    x0 += x1; x1 = rotl32(x1, 26); x1 ^= x0;
    x0 += x1; x1 = rotl32(x1, 6);  x1 ^= x0;
    x0 += ks2; x1 += ks0 + 5u;
    o0 = x0; o1 = x1;
}

__device__ __forceinline__ float gumbel_f(unsigned k0, unsigned k1, unsigned f) {
    unsigned o0, o1;
    tf2x32(k0, k1, 0u, f, o0, o1);
    unsigned bits = o0 ^ o1;
    float u01 = __uint_as_float((bits >> 9) | 0x3F800000u) - 1.0f;
    float u = fmaxf(TINYF, u01 * (1.0f - TINYF) + TINYF);
    return -logf(-logf(u));
}

// ---------------- encoder kernels ----------------

__global__ void k_embed(const float* __restrict__ node, const float* __restrict__ demand,
                        const float* __restrict__ Wn0, const float* __restrict__ bn0,
                        float* __restrict__ h) {
    int idx = blockIdx.x * 256 + threadIdx.x;
    if (idx >= BB * NN * HH) return;
    int r = idx >> 7, c = idx & 127;
    float v = node[r * 2] * Wn0[c] + node[r * 2 + 1] * Wn0[128 + c]
            + demand[r] * Wn0[256 + c] + bn0[c];
    h[idx] = fmaxf(v, 0.0f);
}

__global__ void k_adj(const float* __restrict__ dis, float* __restrict__ A) {
    int row = blockIdx.x;
    const float* d = dis + row * NN;
    int l = threadIdx.x;
    float v0 = (l < NN) ? -d[l] : -__builtin_inff();
    float v1 = (l + 64 < NN) ? -d[l + 64] : -__builtin_inff();
    float m = fmaxf(v0, v1);
    for (int off = 32; off > 0; off >>= 1) m = fmaxf(m, __shfl_xor(m, off));
    float e0 = (l < NN) ? expf(v0 - m) : 0.0f;
    float e1 = (l + 64 < NN) ? expf(v1 - m) : 0.0f;
    float s = e0 + e1;
    for (int off = 32; off > 0; off >>= 1) s += __shfl_xor(s, off);
    float inv = 1.0f / s;
    if (l < NN) A[row * NN + l] = e0 * inv;
    if (l + 64 < NN) A[row * NN + l + 64] = e1 * inv;
}

// out[6400x128] = h[6400x128] @ W[128x128]
__global__ void k_hw(const float* __restrict__ h, const float* __restrict__ W,
                     float* __restrict__ out) {
    __shared__ float hs[8 * 128];
    int block_row = blockIdx.x * 8;
    int tid = threadIdx.x;
    int col = tid & 127;
    int rg = tid >> 7;
    for (int i = tid; i < 8 * 128; i += 256) hs[i] = h[block_row * 128 + i];
    __syncthreads();
    float acc[4] = {0.f, 0.f, 0.f, 0.f};
    for (int k = 0; k < 128; k++) {
        float w = W[k * 128 + col];
#pragma unroll
        for (int r = 0; r < 4; r++) acc[r] += hs[(rg + 2 * r) * 128 + k] * w;
    }
#pragma unroll
    for (int r = 0; r < 4; r++)
        out[(block_row + rg + 2 * r) * 128 + col] = acc[r];
}

// out[6400x384] = h[6400x128] @ W[128x384] + bias[384]
__global__ void k_mm384(const float* __restrict__ h, const float* __restrict__ W,
                        const float* __restrict__ bias, float* __restrict__ out) {
    __shared__ float hs[8 * 128];
    int block_row = blockIdx.x * 8;
    int tid = threadIdx.x;
    int col = blockIdx.y * 128 + (tid & 127);
    int rg = tid >> 7;
    for (int i = tid; i < 8 * 128; i += 256) hs[i] = h[block_row * 128 + i];
    __syncthreads();
    float acc[4] = {0.f, 0.f, 0.f, 0.f};
    for (int k = 0; k < 128; k++) {
        float w = W[k * 384 + col];
#pragma unroll
        for (int r = 0; r < 4; r++) acc[r] += hs[(rg + 2 * r) * 128 + k] * w;
    }
    float b = bias[col];
#pragma unroll
    for (int r = 0; r < 4; r++)
        out[(block_row + rg + 2 * r) * 384 + col] = acc[r] + b;
}

// WqT[k][c] = Wq[c][k]
__global__ void k_transpose128(const float* __restrict__ Wq, float* __restrict__ WqT) {
    int i = blockIdx.x * 256 + threadIdx.x;
    if (i >= 128 * 128) return;
    int k = i >> 7, c = i & 127;
    WqT[k * 128 + c] = Wq[c * 128 + k];
}

__global__ void k_agg(const float* __restrict__ h, const float* __restrict__ Ws,
                      const float* __restrict__ A, const float* __restrict__ hw,
                      float* __restrict__ out) {
    __shared__ float hs[4 * 128];
    __shared__ float As[4 * 100];
    int b = blockIdx.x / 25;
    int i0 = (blockIdx.x % 25) * 4;
    int tid = threadIdx.x;
    int col = tid & 127;
    int rg = tid >> 7;
    int rowbase = b * NN + i0;
    for (int idx = tid; idx < 4 * 128; idx += 256) hs[idx] = h[rowbase * 128 + idx];
    for (int idx = tid; idx < 4 * 100; idx += 256) As[idx] = A[rowbase * 100 + idx];
    __syncthreads();
    float acc0 = 0.f, acc1 = 0.f;
    for (int k = 0; k < 128; k++) {
        float w = Ws[k * 128 + col];
        acc0 += hs[rg * 128 + k] * w;
        acc1 += hs[(rg + 2) * 128 + k] * w;
    }
    const float* hwb = hw + b * NN * 128;
    for (int j = 0; j < NN; j++) {
        float v = hwb[j * 128 + col];
        acc0 += As[rg * 100 + j] * v;
        acc1 += As[(rg + 2) * 100 + j] * v;
    }
    out[(rowbase + rg) * 128 + col]     = fmaxf(acc0, 0.0f);
    out[(rowbase + rg + 2) * 128 + col] = fmaxf(acc1, 0.0f);
}

__global__ void k_predict(const float* __restrict__ dis, const float* __restrict__ We,
                          const float* __restrict__ be, const float* __restrict__ Wc,
                          const float* __restrict__ bc, float* __restrict__ out3) {
    __shared__ float sWe[128], sbe[128], sc0[128], sc1[128];
    int tid = threadIdx.x;
    if (tid < 128) {
        sWe[tid] = We[tid];
        sbe[tid] = be[tid];
        sc0[tid] = Wc[tid * 2];
        sc1[tid] = Wc[tid * 2 + 1];
    }
    __syncthreads();
    float b0 = bc[0], b1 = bc[1];
    for (int pos = blockIdx.x * 256 + tid; pos < BB * NN * NN; pos += gridDim.x * 256) {
        float d = dis[pos];
        float a0 = b0, a1 = b1;
        for (int k = 0; k < 128; k++) {
            float e = fmaxf(d * sWe[k] + sbe[k], 0.0f);
            a0 += e * sc0[k];
            a1 += e * sc1[k];
        }
        float m = fmaxf(a0, a1);
        float p0 = expf(a0 - m), p1 = expf(a1 - m);
        float inv = 1.0f / (p0 + p1);
        out3[pos * 2]     = p0 * inv;
        out3[pos * 2 + 1] = p1 * inv;
    }
}

__global__ void k_zero(float* __restrict__ p, int n) {
    int i = blockIdx.x * 256 + threadIdx.x;
    if (i < n) p[i] = 0.0f;
}

// ---------------- new decoder: 768 threads, precomputed P0 and Z ----------------
// grid = 128 blocks: blockIdx/2 = batch, blockIdx&1 = greedy flag
__global__ __launch_bounds__(768) void k_decode2(
    const float* __restrict__ P0,       // [64*100, 384]  x@Wih0 + bih0
    const float* __restrict__ Z,        // [64*100, 128]  x@Wq^T
    const float* __restrict__ dis,
    const float* __restrict__ Wih,      // [2,128,384]
    const float* __restrict__ Whh,      // [2,128,384]
    const float* __restrict__ bih,      // [2,384]
    const float* __restrict__ bhh,      // [2,384]
    float* __restrict__ out) {
    __shared__ float Zs[NN * 129];
    __shared__ float h0s[128], h1s[128];
    __shared__ float gi0s[T3];
    __shared__ float pg0[2 * T3];
    __shared__ float gi1s[T3], gh1s[T3];
    __shared__ float sbhh0[T3], sbih1[T3], sbhh1[T3];
    __shared__ float pl[4 * NN];
    __shared__ float logits[NN];
    __shared__ float s_m, s_s;
    __shared__ int s_ind;

    const int tid = threadIdx.x;
    const int b = blockIdx.x >> 1;
    const int greedy = blockIdx.x & 1;
    const float SCALE = 0.08838834764831845f;  // 1/sqrt(128) in f32

    const float* Whh0 = Whh;
    const float* Wih1 = Wih + 128 * T3;
    const float* Whh1 = Whh + 128 * T3;

    // stage Z_b into LDS (stride 129)
    for (int idx = tid; idx < NN * 128; idx += 768) {
        int r = idx >> 7, c = idx & 127;
        Zs[r * 129 + c] = Z[(b * NN + r) * 128 + c];
    }
    if (tid < T3) {
        sbhh0[tid] = bhh[tid];
        sbih1[tid] = bih[T3 + tid];
        sbhh1[tid] = bhh[T3 + tid];
    }
    if (tid < 128) { h0s[tid] = 0.0f; h1s[tid] = 0.0f; }

    unsigned kk0, kk1;
    tf2x32(0u, 42u, 0u, 0u, kk0, kk1);

    int last = 0;
    float dist = 0.0f;
    __syncthreads();

    for (int t = 0; t < NN - 1; t++) {
        unsigned sk0, sk1, nk0, nk1;
        tf2x32(kk0, kk1, 0u, 1u, sk0, sk1);
        tf2x32(kk0, kk1, 0u, 0u, nk0, nk1);
        kk0 = nk0; kk1 = nk1;

        // ---- phase A: gh0 partials (k-split 2-way) + gi0 row fetch ----
        {
            const float* P0row = P0 + (b * NN + last) * T3;
            if (tid < T3) {
                int j = tid;
                float acc = 0.0f;
#pragma unroll 16
                for (int k = 0; k < 64; k++) acc += h0s[k] * Whh0[k * T3 + j];
                pg0[j] = acc;
                gi0s[j] = P0row[j];
            } else {
                int j = tid - T3;
                float acc = 0.0f;
#pragma unroll 16
                for (int k = 64; k < 128; k++) acc += h0s[k] * Whh0[k * T3 + j];
                pg0[T3 + j] = acc;
            }
        }
        __syncthreads();

        // ---- phase B: h0 update ----
        if (tid < 128) {
            float ghr = pg0[tid] + pg0[T3 + tid] + sbhh0[tid];
            float ghz = pg0[tid + 128] + pg0[T3 + tid + 128] + sbhh0[tid + 128];
            float ghn = pg0[tid + 256] + pg0[T3 + tid + 256] + sbhh0[tid + 256];
            float r = 1.0f / (1.0f + expf(-(gi0s[tid] + ghr)));
            float z = 1.0f / (1.0f + expf(-(gi0s[tid + 128] + ghz)));
            float n = tanhf(gi0s[tid + 256] + r * ghn);
            h0s[tid] = (1.0f - z) * n + z * h0s[tid];
        }
        __syncthreads();

        // ---- phase C: gi1 (from new h0) and gh1 (from old h1), full dots ----
        if (tid < T3) {
            int j = tid;
            float acc = sbih1[j];
#pragma unroll 16
            for (int k = 0; k < 128; k++) acc += h0s[k] * Wih1[k * T3 + j];
            gi1s[j] = acc;
        } else {
            int j = tid - T3;
            float acc = sbhh1[j];
#pragma unroll 16
            for (int k = 0; k < 128; k++) acc += h1s[k] * Whh1[k * T3 + j];
            gh1s[j] = acc;
        }
        __syncthreads();

        // ---- phase D: h1 update ----
        if (tid < 128) {
            float r = 1.0f / (1.0f + expf(-(gi1s[tid] + gh1s[tid])));
            float z = 1.0f / (1.0f + expf(-(gi1s[tid + 128] + gh1s[tid + 128])));
            float n = tanhf(gi1s[tid + 256] + r * gh1s[tid + 256]);
            h1s[tid] = (1.0f - z) * n + z * h1s[tid];
        }
        __syncthreads();

        // ---- phase E: logits partials, (n in 100) x (part in 4), 32 k each ----
        if (tid < 400) {
            int n = tid % 100, p = tid / 100;
            int k0 = p * 32;
            float acc = 0.0f;
#pragma unroll
            for (int kk = 0; kk < 32; kk++) acc += h1s[k0 + kk] * Zs[n * 129 + k0 + kk];
            pl[p * 100 + n] = acc;
        }
        __syncthreads();

        // ---- phase F: combine + softmax stats + (gumbel-)argmax, wave 0 ----
        if (tid < 64) {
            float v0 = -__builtin_inff(), v1 = -__builtin_inff();
            {
                int n = tid;
                v0 = (pl[n] + pl[100 + n] + pl[200 + n] + pl[300 + n]) * SCALE;
                logits[n] = v0;
            }
            if (tid + 64 < NN) {
                int n = tid + 64;
                v1 = (pl[n] + pl[100 + n] + pl[200 + n] + pl[300 + n]) * SCALE;
                logits[n] = v1;
            }
            float m = fmaxf(v0, v1);
            for (int off = 32; off > 0; off >>= 1) m = fmaxf(m, __shfl_xor(m, off));
            float e = expf(v0 - m) + ((tid + 64 < NN) ? expf(v1 - m) : 0.0f);
            for (int off = 32; off > 0; off >>= 1) e += __shfl_xor(e, off);
            float a0 = v0, a1 = v1;
            if (!greedy) {
                a0 = v0 + gumbel_f(sk0, sk1, (unsigned)(b * NN + tid));
                if (tid + 64 < NN) a1 = v1 + gumbel_f(sk0, sk1, (unsigned)(b * NN + tid + 64));
            }
            float bv; int bi;
            if (a1 > a0) { bv = a1; bi = tid + 64; } else { bv = a0; bi = tid; }
            for (int off = 32; off > 0; off >>= 1) {
                float ov = __shfl_xor(bv, off);
                int   oi = __shfl_xor(bi, off);
                if (ov > bv || (ov == bv && oi < bi)) { bv = ov; bi = oi; }
            }
            if (tid == 0) { s_m = m; s_s = e; s_ind = bi; }
        }
        __syncthreads();
        int ind = s_ind;
        if (tid == 0) {
            if (!greedy) out[O0 + b * (NN - 1) + t] = logits[ind] - s_m - logf(s_s);
            dist += dis[b * NN * NN + last * NN + ind];
            if (greedy) out[O4 + b * NN * NN + last * NN + ind] = 1.0f;
        }
        last = ind;
        __syncthreads();
    }
    if (tid == 0) {
        if (!greedy) out[O1 + b] = dist;
        else         out[O2 + b] = dist;
    }
}

// ---------------- fallback decoder (round-1, needs only 12.4 MB ws) ----------------
__device__ __forceinline__ void gru_layer(const float* __restrict__ xin,
                                          float* __restrict__ hstate,
                                          const float* __restrict__ Wih,
                                          const float* __restrict__ Whh,
                                          const float* __restrict__ bih,
                                          const float* __restrict__ bhh,
                                          float* gi, float* gh, int tid) {
    for (int j = tid; j < T3; j += 256) {
        float ai = bih[j], ah = bhh[j];
        const float* wi = Wih + j;
        const float* wh = Whh + j;
        for (int k = 0; k < 128; k++) {
            ai += xin[k] * wi[k * T3];
            ah += hstate[k] * wh[k * T3];
        }
        gi[j] = ai; gh[j] = ah;
    }
    __syncthreads();
    if (tid < 128) {
        float r = 1.0f / (1.0f + expf(-(gi[tid] + gh[tid])));
        float z = 1.0f / (1.0f + expf(-(gi[128 + tid] + gh[128 + tid])));
        float n = tanhf(gi[256 + tid] + r * gh[256 + tid]);
        hstate[tid] = (1.0f - z) * n + z * hstate[tid];
    }
    __syncthreads();
}

__global__ __launch_bounds__(256) void k_decode(
    const float* __restrict__ x, const float* __restrict__ dis,
    const float* __restrict__ Wih, const float* __restrict__ Whh,
    const float* __restrict__ bih, const float* __restrict__ bhh,
    const float* __restrict__ Wq, float* __restrict__ out) {
    __shared__ float xs[NN * 129];
    __shared__ float h0[128], h1[128];
    __shared__ float gi[T3], gh[T3];
    __shared__ float q[128];
    __shared__ float logits[NN];
    __shared__ float s_m, s_s;
    __shared__ int s_ind;

    const int tid = threadIdx.x;
    const int b = blockIdx.x >> 1;
    const int greedy = blockIdx.x & 1;
    const float SCALE = 0.08838834764831845f;

    for (int idx = tid; idx < NN * 128; idx += 256) {
        int r = idx >> 7, c = idx & 127;
        xs[r * 129 + c] = x[(b * NN + r) * 128 + c];
    }
    if (tid < 128) { h0[tid] = 0.0f; h1[tid] = 0.0f; }

    unsigned kk0, kk1;
    tf2x32(0u, 42u, 0u, 0u, kk0, kk1);

    int last = 0;
    float dist = 0.0f;
    __syncthreads();

    for (int t = 0; t < NN - 1; t++) {
        unsigned sk0, sk1, nk0, nk1;
        tf2x32(kk0, kk1, 0u, 1u, sk0, sk1);
        tf2x32(kk0, kk1, 0u, 0u, nk0, nk1);
        kk0 = nk0; kk1 = nk1;

        gru_layer(&xs[last * 129], h0, Wih, Whh, bih, bhh, gi, gh, tid);
        gru_layer(h0, h1, Wih + 128 * T3, Whh + 128 * T3, bih + T3, bhh + T3, gi, gh, tid);

        if (tid < 128) {
            float acc = 0.0f;
            for (int k = 0; k < 128; k++) acc += h1[k] * Wq[k * 128 + tid];
            q[tid] = acc;
        }
        __syncthreads();
        if (tid < NN) {
            float acc = 0.0f;
            for (int k = 0; k < 128; k++) acc += q[k] * xs[tid * 129 + k];
            logits[tid] = acc * SCALE;
        }
        __syncthreads();
        if (tid < 64) {
            float v0 = (tid < NN) ? logits[tid] : -__builtin_inff();
            float v1 = (tid + 64 < NN) ? logits[tid + 64] : -__builtin_inff();
            float m = fmaxf(v0, v1);
            for (int off = 32; off > 0; off >>= 1) m = fmaxf(m, __shfl_xor(m, off));
            float e = ((tid < NN) ? expf(v0 - m) : 0.0f)
                    + ((tid + 64 < NN) ? expf(v1 - m) : 0.0f);
            for (int off = 32; off > 0; off >>= 1) e += __shfl_xor(e, off);
            float a0 = v0, a1 = v1;
            if (!greedy) {
                if (tid < NN)      a0 = v0 + gumbel_f(sk0, sk1, (unsigned)(b * NN + tid));
                if (tid + 64 < NN) a1 = v1 + gumbel_f(sk0, sk1, (unsigned)(b * NN + tid + 64));
            }
            float bv; int bi;
            if (a1 > a0) { bv = a1; bi = tid + 64; } else { bv = a0; bi = tid; }
            for (int off = 32; off > 0; off >>= 1) {
                float ov = __shfl_xor(bv, off);
                int   oi = __shfl_xor(bi, off);
                if (ov > bv || (ov == bv && oi < bi)) { bv = ov; bi = oi; }
            }
            if (tid == 0) { s_m = m; s_s = e; s_ind = bi; }
        }
        __syncthreads();
        int ind = s_ind;
        if (tid == 0) {
            if (!greedy) out[O0 + b * (NN - 1) + t] = logits[ind] - s_m - logf(s_s);
            dist += dis[b * NN * NN + last * NN + ind];
            if (greedy) out[O4 + b * NN * NN + last * NN + ind] = 1.0f;
        }
        last = ind;
        __syncthreads();
    }
    if (tid == 0) {
        if (!greedy) out[O1 + b] = dist;
        else         out[O2 + b] = dist;
    }
}

// ---------------- host launcher ----------------
extern "C" void kernel_launch(void* const* d_in, const int* in_sizes, int n_in,
                              void* d_out, int out_size, void* d_ws, size_t ws_size,
                              hipStream_t stream) {
    (void)in_sizes; (void)n_in; (void)out_size;
    const float* node   = (const float*)d_in[0];
    const float* demand = (const float*)d_in[1];
    const float* dis    = (const float*)d_in[2];
    const float* Wn0    = (const float*)d_in[3];
    const float* bn0    = (const float*)d_in[4];
    const float* Ws     = (const float*)d_in[5];
    const float* Wngh   = (const float*)d_in[6];
    const float* We     = (const float*)d_in[7];
    const float* be     = (const float*)d_in[8];
    const float* Wih    = (const float*)d_in[9];
    const float* Whh    = (const float*)d_in[10];
    const float* bih    = (const float*)d_in[11];
    const float* bhh    = (const float*)d_in[12];
    const float* Wq     = (const float*)d_in[13];
    const float* Wc     = (const float*)d_in[14];
    const float* bc     = (const float*)d_in[15];
    float* out = (float*)d_out;
    float* ws  = (float*)d_ws;

    // ws layout (floats):
    // hA:   0       .. 819200
    // hB:   819200  .. 1638400
    // hw/Z: 1638400 .. 2457600   (hw during encoder; Z after)
    // A:    2457600 .. 3097600   (A during encoder; P0 overlays from 2457600)
    // P0:   2457600 .. 4915200
    // WqT:  4915200 .. 4931584
    float* hA  = ws;
    float* hB  = ws + 819200;
    float* hw  = ws + 1638400;
    float* A   = ws + 2457600;
    float* P0  = ws + 2457600;
    float* WqT = ws + 4915200;
    const size_t need_bytes = (size_t)4931584 * 4;
    const bool big_ws = ws_size >= need_bytes;

    hipLaunchKernelGGL(k_embed, dim3(3200), dim3(256), 0, stream, node, demand, Wn0, bn0, hA);
    hipLaunchKernelGGL(k_adj, dim3(6400), dim3(64), 0, stream, dis, A);

    float* cur = hA;
    float* nxt = hB;
    for (int l = 0; l < 3; l++) {
        hipLaunchKernelGGL(k_hw, dim3(800), dim3(256), 0, stream, cur, Wngh + l * 16384, hw);
        hipLaunchKernelGGL(k_agg, dim3(1600), dim3(256), 0, stream, cur, Ws + l * 16384, A, hw, nxt);
        float* tswap = cur; cur = nxt; nxt = tswap;
    }
    // cur == hB holds the final encoder output

    hipLaunchKernelGGL(k_predict, dim3(2500), dim3(256), 0, stream, dis, We, be, Wc, bc, out + O3);
    hipLaunchKernelGGL(k_zero, dim3(2500), dim3(256), 0, stream, out + O4, BB * NN * NN);

    if (big_ws) {
        // Z = h @ Wq^T  (into hw region, free after encoder)
        hipLaunchKernelGGL(k_transpose128, dim3(64), dim3(256), 0, stream, Wq, WqT);
        hipLaunchKernelGGL(k_hw, dim3(800), dim3(256), 0, stream, cur, WqT, hw);
        // P0 = h @ Wih0 + bih0 (overlays A region, free after encoder)
        hipLaunchKernelGGL(k_mm384, dim3(800, 3), dim3(256), 0, stream, cur, Wih, bih, P0);
        hipLaunchKernelGGL(k_decode2, dim3(128), dim3(768), 0, stream,
                           P0, hw, dis, Wih, Whh, bih, bhh, out);
    } else {
        hipLaunchKernelGGL(k_decode, dim3(128), dim3(256), 0, stream,
                           cur, dis, Wih, Whh, bih, bhh, Wq, out);
    }
}